// Round 5
// baseline (1059.771 us; speedup 1.0000x reference)
//
#include <hip/hip_runtime.h>
#include <math.h>

#define NA   20000
#define PE   320000
#define FDIM 128
#define ET   64          // edges per block (edge kernel)
#define AT   32          // atoms per block (node kernel)

typedef unsigned short ushort_t;
typedef __attribute__((ext_vector_type(8))) short bf16x8;
typedef __attribute__((ext_vector_type(4))) float f32x4;
#define MFMA16 __builtin_amdgcn_mfma_f32_16x16x32_bf16

// ---------------- edge kernel LDS map (bytes) ----------------
// x' layout (words): [rbf 0:64 | a* 64:224 | si 224:352 | sj 352:480]
#define XSTR     482        // ushort stride; %32==2 -> 2-way (free)
#define HSTR     132        // ushort stride; %32==4
#define XS_OFF   0          // ushort [64][482]
#define H1_OFF   61696      // ushort [64][132]  h1_eq -> h1_inv
#define US_OFF   78592      // float  [64][4]    ux,uy,uz,cut
#define IIS_OFF  79616      // int [65]
#define JJS_OFF  79876      // int [64]
#define SMEM_SZ  80136
// f32 aliases over xs (xs dead after GEMM1)
#define GL_OFF   0          // float [64][68]   g     (17408 B)
#define ML_OFF   17408      // float [64][132]  m     (33792 B, ends 51200)

// ---------------- packed-weight fragment bases (1 frag = 8 ushort = 16B) ----
// fused W1: 15 kb x 8 ct x 64 lanes = 7680 frags
#define PK_W1EQ0   0
#define PK_W1EQ1   7680
#define PK_W1INV0  15360
#define PK_W1INV1  23040
#define PK_W2EQ0   30720    // 4kb x 4ct x 64 = 1024
#define PK_W2EQ1   31744
#define PK_W2INV0  32768    // 4kb x 8ct x 64 = 2048
#define PK_W2INV1  34816
#define PK_WEMB    36864    // 2048
#define PK_W1U0    38912    // 8kb x 8ct x 64 = 4096
#define PK_W1U1    43008
#define PK_W2U0    47104    // 2048
#define PK_W2U1    49152
#define PK_TOTAL   51200

__device__ __forceinline__ float silu_f(float z) {
    return z / (1.0f + __expf(-z));
}

__device__ __forceinline__ ushort_t f2bf(float x) {
    __bf16 h = (__bf16)x;
    union { __bf16 b; ushort_t u; } c; c.b = h; return c.u;
}

__device__ __forceinline__ unsigned int pack2bf(float x, float y) {
    return (unsigned int)f2bf(x) | ((unsigned int)f2bf(y) << 16);
}

__device__ __forceinline__ uint4 cvt8(float4 a, float4 b) {
    uint4 r;
    r.x = pack2bf(a.x, a.y); r.y = pack2bf(a.z, a.w);
    r.z = pack2bf(b.x, b.y); r.w = pack2bf(b.z, b.w);
    return r;
}

// ---------------------------------------------------------------------------
// Pack weights into bf16 MFMA B-fragment order.
// W1 sections are FUSED over x' = [rbf(64) | a*(160) | si(128) | sj(128)]:
//   row k<64:        Wrbf[k] @ W1[0:32]                  (dot only)
//   row 64<=k<224:   W1[k-32]                            (mode0) / 0 (mode1)
//   row k>=224:      W1direct + Wrbf[k-160] @ W1[0:32]
//   mode0 direct: W1[k-32]; mode1 (eq0, 288 rows): W1[k-192]
// ---------------------------------------------------------------------------
__global__ void pack_all(const float* __restrict__ eq0W1, const float* __restrict__ eq1W1,
                         const float* __restrict__ invW1, const float* __restrict__ eq0W2,
                         const float* __restrict__ eq1W2, const float* __restrict__ invW2,
                         const float* __restrict__ Wrbf,  const float* __restrict__ Wemb,
                         const float* __restrict__ updW1, const float* __restrict__ updW2,
                         ushort_t* __restrict__ out)
{
    const int tid = blockIdx.x * blockDim.x + threadIdx.x;
    if (tid >= PK_TOTAL) return;
    int base, KB, N, fused = 0, mode = 0;
    const float* src;
    if      (tid < PK_W1EQ1)  { base = PK_W1EQ0;  KB = 15; N = 128; src = eq0W1; fused = 1; mode = 1; }
    else if (tid < PK_W1INV0) { base = PK_W1EQ1;  KB = 15; N = 128; src = eq1W1; fused = 1; }
    else if (tid < PK_W1INV1) { base = PK_W1INV0; KB = 15; N = 128; src = invW1; fused = 1; }
    else if (tid < PK_W2EQ0)  { base = PK_W1INV1; KB = 15; N = 128; src = invW1 + 448 * 128; fused = 1; }
    else if (tid < PK_W2EQ1)  { base = PK_W2EQ0;  KB = 4;  N = 64;  src = eq0W2; }
    else if (tid < PK_W2INV0) { base = PK_W2EQ1;  KB = 4;  N = 64;  src = eq1W2; }
    else if (tid < PK_W2INV1) { base = PK_W2INV0; KB = 4;  N = 128; src = invW2; }
    else if (tid < PK_WEMB)   { base = PK_W2INV1; KB = 4;  N = 128; src = invW2 + 128 * 128; }
    else if (tid < PK_W1U0)   { base = PK_WEMB;   KB = 4;  N = 128; src = Wemb; }
    else if (tid < PK_W1U1)   { base = PK_W1U0;   KB = 8;  N = 128; src = updW1; }
    else if (tid < PK_W2U0)   { base = PK_W1U1;   KB = 8;  N = 128; src = updW1 + 256 * 128; }
    else if (tid < PK_W2U1)   { base = PK_W2U0;   KB = 4;  N = 128; src = updW2; }
    else                      { base = PK_W2U1;   KB = 4;  N = 128; src = updW2 + 128 * 128; }
    const int local = tid - base;
    const int lane  = local & 63;
    const int rest  = local >> 6;
    const int kb    = rest % KB;
    const int ct    = rest / KB;
    const int col   = ct * 16 + (lane & 15);
    const int k0    = kb * 32 + ((lane >> 4) * 8);
    ushort_t v[8];
    #pragma unroll
    for (int j = 0; j < 8; j++) {
        const int k = k0 + j;
        float x;
        if (!fused) {
            x = src[(size_t)k * N + col];
        } else {
            x = 0.f;
            const int di = (mode == 0) ? (k >= 64 ? k - 32 : -1)
                                       : (k >= 224 ? k - 192 : -1);
            if (di >= 0) x = src[(size_t)di * 128 + col];
            const int dr = (k < 64) ? k : (k >= 224 ? k - 160 : -1);
            if (dr >= 0) {
                float s = 0.f;
                for (int q = 0; q < 32; q++)
                    s += Wrbf[dr * 32 + q] * src[(size_t)q * 128 + col];
                x += s;
            }
        }
        v[j] = f2bf(x);
    }
    *(uint4*)(out + (size_t)tid * 8) = *(uint4*)v;
}

// ---------------------------------------------------------------------------
// Fused MFMA edge kernel. 64 edges/block, 512 threads (8 waves), 2 blocks/CU.
// eqSkip=1 also implies v_in == 0 (pass 1): a_* phase and kb 2..6 skipped.
// ---------------------------------------------------------------------------
__global__ __launch_bounds__(512, 4)
void edge_kernel(const float* __restrict__ rbfs,
                 const float* __restrict__ dists,
                 const float* __restrict__ vecs,
                 const float* __restrict__ cuts,
                 const int*   __restrict__ gidx_i,
                 const int*   __restrict__ gidx_j,
                 const ushort_t* __restrict__ s_bf,    // bf16 mirror of s
                 const float* __restrict__ v_in,
                 const ushort_t* __restrict__ pW1eq,
                 const float* __restrict__ b1eq,
                 const ushort_t* __restrict__ pW2eq,
                 const ushort_t* __restrict__ pW1inv,
                 const float* __restrict__ b1inv,
                 const ushort_t* __restrict__ pW2inv,
                 const float* __restrict__ b2inv,
                 float* __restrict__ s_out,
                 float* __restrict__ v_out,
                 const int eqSkip)
{
    __shared__ __align__(16) char smem[SMEM_SZ];
    ushort_t* xs  = (ushort_t*)(smem + XS_OFF);
    ushort_t* h1  = (ushort_t*)(smem + H1_OFF);
    float*    us  = (float*)(smem + US_OFF);
    int*      iis = (int*)(smem + IIS_OFF);
    int*      jjs = (int*)(smem + JJS_OFF);
    float*    gl  = (float*)(smem + GL_OFF);
    float*    ml  = (float*)(smem + ML_OFF);

    const int t    = threadIdx.x;
    // XCD-aware swizzle: 5000 blocks = 8 XCDs x 625 contiguous chunks
    const int bid  = blockIdx.x;
    const int p0   = ((bid & 7) * 625 + (bid >> 3)) * ET;
    const int lane = t & 63;
    const int wid  = t >> 6;
    const int colf = lane & 15;
    const int krow = (lane >> 4) * 8;

    // ------- phase 0: stage rbf/si/sj -> xs, us/iis/jjs; a_* (pass 2 only) ----
    {
        const int e = t >> 3, l = t & 7;
        const int p = p0 + e;
        const int i = gidx_i[p];
        const int j = gidx_j[p];
        const uint4* si4 = (const uint4*)(s_bf + (size_t)i * FDIM);
        const uint4* sj4 = (const uint4*)(s_bf + (size_t)j * FDIM);
        *(uint4*)&xs[e * XSTR + 224 + l * 16]     = si4[l * 2];
        *(uint4*)&xs[e * XSTR + 224 + l * 16 + 8] = si4[l * 2 + 1];
        *(uint4*)&xs[e * XSTR + 352 + l * 16]     = sj4[l * 2];
        *(uint4*)&xs[e * XSTR + 352 + l * 16 + 8] = sj4[l * 2 + 1];
        const float4* rb4 = (const float4*)(rbfs + (size_t)p * 64);
        float4 r0 = rb4[l * 2], r1 = rb4[l * 2 + 1];
        *(uint4*)&xs[e * XSTR + l * 8] = cvt8(r0, r1);
        if (t < ET) {
            const int pp = p0 + t;
            const float dinv = 1.0f / (dists[pp] + 0.001f);
            float4 uu;
            uu.x = vecs[pp * 3 + 0] * dinv;
            uu.y = vecs[pp * 3 + 1] * dinv;
            uu.z = vecs[pp * 3 + 2] * dinv;
            uu.w = cuts[pp];
            *(float4*)&us[t * 4] = uu;
            jjs[t] = gidx_j[pp];
        }
        if (t < ET + 1) {
            const int pp = p0 + t;
            iis[t] = (pp < PE) ? gidx_i[pp] : -1;
        }
        if (!eqSkip) {
            // a_* terms -> xs cols [64,224)
            const int m0 = (t & 7) * 4;
            const float dinv = 1.0f / (dists[p] + 0.001f);
            const float ux = vecs[p * 3 + 0] * dinv;
            const float uy = vecs[p * 3 + 1] * dinv;
            const float uz = vecs[p * 3 + 2] * dinv;
            float vi[3][4], vj[3][4];
            #pragma unroll
            for (int d = 0; d < 3; d++) {
                const float4 a = *(const float4*)(v_in + (size_t)i * 96 + d * 32 + m0);
                const float4 b = *(const float4*)(v_in + (size_t)j * 96 + d * 32 + m0);
                vi[d][0] = a.x; vi[d][1] = a.y; vi[d][2] = a.z; vi[d][3] = a.w;
                vj[d][0] = b.x; vj[d][1] = b.y; vj[d][2] = b.z; vj[d][3] = b.w;
            }
            float aui[4], auj[4], aij[4], aii[4], ajj[4];
            #pragma unroll
            for (int mm = 0; mm < 4; mm++) {
                aui[mm] = ux * vi[0][mm] + uy * vi[1][mm] + uz * vi[2][mm];
                auj[mm] = ux * vj[0][mm] + uy * vj[1][mm] + uz * vj[2][mm];
                aij[mm] = vi[0][mm] * vj[0][mm] + vi[1][mm] * vj[1][mm] + vi[2][mm] * vj[2][mm];
                aii[mm] = vi[0][mm] * vi[0][mm] + vi[1][mm] * vi[1][mm] + vi[2][mm] * vi[2][mm];
                ajj[mm] = vj[0][mm] * vj[0][mm] + vj[1][mm] * vj[1][mm] + vj[2][mm] * vj[2][mm];
            }
            uint2 w;
            w.x = pack2bf(aui[0], aui[1]); w.y = pack2bf(aui[2], aui[3]);
            *(uint2*)&xs[e * XSTR + 64 + m0] = w;
            w.x = pack2bf(auj[0], auj[1]); w.y = pack2bf(auj[2], auj[3]);
            *(uint2*)&xs[e * XSTR + 96 + m0] = w;
            w.x = pack2bf(aij[0], aij[1]); w.y = pack2bf(aij[2], aij[3]);
            *(uint2*)&xs[e * XSTR + 128 + m0] = w;
            w.x = pack2bf(aii[0], aii[1]); w.y = pack2bf(aii[2], aii[3]);
            *(uint2*)&xs[e * XSTR + 160 + m0] = w;
            w.x = pack2bf(ajj[0], ajj[1]); w.y = pack2bf(ajj[2], ajj[3]);
            *(uint2*)&xs[e * XSTR + 192 + m0] = w;
        }
    }
    __syncthreads();   // B1: x' complete

    // ------- GEMM1 (fused eq+inv): 15 kb over x' ------------------------------
    f32x4 ainv[4];
    {
        f32x4 aeq[4];
        const float bce = b1eq[wid * 16 + colf];
        const float bci = b1inv[wid * 16 + colf];
        #pragma unroll
        for (int rt = 0; rt < 4; rt++) {
            aeq[rt]  = (f32x4){bce, bce, bce, bce};
            ainv[rt] = (f32x4){bci, bci, bci, bci};
        }
        #pragma unroll
        for (int kb = 0; kb < 15; kb++) {
            if (eqSkip && kb >= 2 && kb < 7) continue;   // a* rows are zero in pass 1
            bf16x8 af[4];
            #pragma unroll
            for (int rt = 0; rt < 4; rt++)
                af[rt] = *(const bf16x8*)&xs[(rt * 16 + colf) * XSTR + kb * 32 + krow];
            bf16x8 bi = *(const bf16x8*)(pW1inv + ((size_t)(wid * 15 + kb) * 64 + lane) * 8);
            #pragma unroll
            for (int rt = 0; rt < 4; rt++)
                ainv[rt] = MFMA16(af[rt], bi, ainv[rt], 0, 0, 0);
            bf16x8 be = *(const bf16x8*)(pW1eq + ((size_t)(wid * 15 + kb) * 64 + lane) * 8);
            #pragma unroll
            for (int rt = 0; rt < 4; rt++)
                aeq[rt] = MFMA16(af[rt], be, aeq[rt], 0, 0, 0);
        }
        #pragma unroll
        for (int rt = 0; rt < 4; rt++)
            #pragma unroll
            for (int r = 0; r < 4; r++) {
                const int row = rt * 16 + (lane >> 4) * 4 + r;
                h1[row * HSTR + wid * 16 + colf] = f2bf(silu_f(aeq[rt][r]));
            }
    }
    __syncthreads();   // B2: h1_eq ready; xs dead (gl/ml aliases free)

    // ------- GEMM2-eq: g = h1_eq @ W2eq -> gl (xs alias) ----------------------
    {
        const int ct2 = wid & 3;
        const int rh  = wid >> 2;
        f32x4 gacc[2];
        gacc[0] = (f32x4){0.f, 0.f, 0.f, 0.f};
        gacc[1] = (f32x4){0.f, 0.f, 0.f, 0.f};
        #pragma unroll
        for (int kb = 0; kb < 4; kb++) {
            bf16x8 bf = *(const bf16x8*)(pW2eq + ((size_t)(ct2 * 4 + kb) * 64 + lane) * 8);
            #pragma unroll
            for (int q = 0; q < 2; q++) {
                bf16x8 af = *(const bf16x8*)&h1[((rh * 2 + q) * 16 + colf) * HSTR + kb * 32 + krow];
                gacc[q] = MFMA16(af, bf, gacc[q], 0, 0, 0);
            }
        }
        #pragma unroll
        for (int q = 0; q < 2; q++)
            #pragma unroll
            for (int r = 0; r < 4; r++) {
                const int row = (rh * 2 + q) * 16 + (lane >> 4) * 4 + r;
                gl[row * 68 + ct2 * 16 + colf] = gacc[q][r];
            }
    }
    __syncthreads();   // B3: h1_eq reads done

    // ------- write h1_inv -----------------------------------------------------
    {
        #pragma unroll
        for (int rt = 0; rt < 4; rt++)
            #pragma unroll
            for (int r = 0; r < 4; r++) {
                const int row = rt * 16 + (lane >> 4) * 4 + r;
                h1[row * HSTR + wid * 16 + colf] = f2bf(silu_f(ainv[rt][r]));
            }
    }
    __syncthreads();   // B4: h1_inv ready

    // ------- GEMM2-inv: m = silu(h1_inv @ W2inv + b2) * cut -> ml (xs alias) --
    {
        f32x4 macc[4];
        const float bc = b2inv[wid * 16 + colf];
        #pragma unroll
        for (int rt = 0; rt < 4; rt++) macc[rt] = (f32x4){bc, bc, bc, bc};
        #pragma unroll
        for (int kb = 0; kb < 4; kb++) {
            bf16x8 bf = *(const bf16x8*)(pW2inv + ((size_t)(wid * 4 + kb) * 64 + lane) * 8);
            #pragma unroll
            for (int rt = 0; rt < 4; rt++) {
                bf16x8 af = *(const bf16x8*)&h1[(rt * 16 + colf) * HSTR + kb * 32 + krow];
                macc[rt] = MFMA16(af, bf, macc[rt], 0, 0, 0);
            }
        }
        #pragma unroll
        for (int rt = 0; rt < 4; rt++)
            #pragma unroll
            for (int r = 0; r < 4; r++) {
                const int row = rt * 16 + (lane >> 4) * 4 + r;
                ml[row * 132 + wid * 16 + colf] = silu_f(macc[rt][r]) * us[row * 4 + 3];
            }
    }
    __syncthreads();   // B5: ml/gl ready

    // ------- sorted-run scan + scatter (4 x 16-edge quarters) -----------------
    {
        // s columns: 512 threads = 4 quarters x 128 cols, 16 iters
        const int qq = t >> 7;
        const int c  = t & 127;
        const int e0 = qq * 16;
        float acc = 0.f;
        #pragma unroll
        for (int e = e0; e < e0 + 16; e++) {
            acc += ml[e * 132 + c];
            if (e == e0 + 15 || iis[e + 1] != iis[e]) {
                atomicAdd(&s_out[(size_t)iis[e] * FDIM + c], acc);
                acc = 0.f;
            }
        }
    }
    if (t < 384) {
        // v columns: 4 quarters x 96 cols, 16 iters
        const int qq  = t / 96;
        const int c   = t - qq * 96;
        const int d   = c >> 5;
        const int mm  = c & 31;
        const int e0  = qq * 16;
        float acc = 0.f;
        #pragma unroll
        for (int e = e0; e < e0 + 16; e++) {
            const float g0  = gl[e * 68 + mm];
            const float g1  = gl[e * 68 + 32 + mm];
            const float vjv = v_in[(size_t)jjs[e] * 96 + c];
            acc = fmaf(us[e * 4 + 3], fmaf(g0, us[e * 4 + d], g1 * vjv), acc);
            if (e == e0 + 15 || iis[e + 1] != iis[e]) {
                atomicAdd(&v_out[(size_t)iis[e] * 96 + c], acc);
                acc = 0.f;
            }
        }
    }
}

// ---------------------------------------------------------------------------
// MFMA node update: s_out = s_in + silu(silu([s,s@Wemb]@W1u+b1u)@W2u+b2u)
// ---------------------------------------------------------------------------
__global__ __launch_bounds__(256, 6)
void node_kernel(const float* __restrict__ s_in,
                 const ushort_t* __restrict__ pWemb,
                 const ushort_t* __restrict__ pW1u,
                 const float* __restrict__ b1u,
                 const ushort_t* __restrict__ pW2u,
                 const float* __restrict__ b2u,
                 float* __restrict__ s_out,
                 ushort_t* __restrict__ sbf_out)
{
    __shared__ ushort_t ss[AT * HSTR];
    __shared__ ushort_t fe[AT * HSTR];
    __shared__ ushort_t t1[AT * HSTR];
    const int t    = threadIdx.x;
    const int a0   = blockIdx.x * AT;
    const int lane = t & 63;
    const int wid  = t >> 6;
    const int colf = lane & 15;
    const int krow = (lane >> 4) * 8;

    {
        const int a = t >> 3, l = t & 7;
        const float4* sr = (const float4*)(s_in + (size_t)(a0 + a) * FDIM);
        float4 q0 = sr[l * 4 + 0], q1 = sr[l * 4 + 1], q2 = sr[l * 4 + 2], q3 = sr[l * 4 + 3];
        *(uint4*)&ss[a * HSTR + l * 16]     = cvt8(q0, q1);
        *(uint4*)&ss[a * HSTR + l * 16 + 8] = cvt8(q2, q3);
    }
    __syncthreads();

    #pragma unroll
    for (int ci = 0; ci < 2; ci++) {
        const int ct = wid * 2 + ci;
        f32x4 acc[2];
        acc[0] = (f32x4){0.f, 0.f, 0.f, 0.f};
        acc[1] = (f32x4){0.f, 0.f, 0.f, 0.f};
        #pragma unroll
        for (int kb = 0; kb < 4; kb++) {
            bf16x8 bf = *(const bf16x8*)(pWemb + ((size_t)(ct * 4 + kb) * 64 + lane) * 8);
            #pragma unroll
            for (int rt = 0; rt < 2; rt++) {
                bf16x8 af = *(const bf16x8*)&ss[(rt * 16 + colf) * HSTR + kb * 32 + krow];
                acc[rt] = MFMA16(af, bf, acc[rt], 0, 0, 0);
            }
        }
        #pragma unroll
        for (int rt = 0; rt < 2; rt++)
            #pragma unroll
            for (int r = 0; r < 4; r++) {
                const int row = rt * 16 + (lane >> 4) * 4 + r;
                fe[row * HSTR + ct * 16 + colf] = f2bf(acc[rt][r]);
            }
    }
    __syncthreads();

    #pragma unroll
    for (int ci = 0; ci < 2; ci++) {
        const int ct = wid * 2 + ci;
        const float bc = b1u[ct * 16 + colf];
        f32x4 acc[2];
        acc[0] = (f32x4){bc, bc, bc, bc};
        acc[1] = (f32x4){bc, bc, bc, bc};
        #pragma unroll
        for (int kb = 0; kb < 8; kb++) {
            bf16x8 bf = *(const bf16x8*)(pW1u + ((size_t)(ct * 8 + kb) * 64 + lane) * 8);
            #pragma unroll
            for (int rt = 0; rt < 2; rt++) {
                bf16x8 af;
                if (kb < 4) af = *(const bf16x8*)&ss[(rt * 16 + colf) * HSTR + kb * 32 + krow];
                else        af = *(const bf16x8*)&fe[(rt * 16 + colf) * HSTR + (kb - 4) * 32 + krow];
                acc[rt] = MFMA16(af, bf, acc[rt], 0, 0, 0);
            }
        }
        #pragma unroll
        for (int rt = 0; rt < 2; rt++)
            #pragma unroll
            for (int r = 0; r < 4; r++) {
                const int row = rt * 16 + (lane >> 4) * 4 + r;
                t1[row * HSTR + ct * 16 + colf] = f2bf(silu_f(acc[rt][r]));
            }
    }
    __syncthreads();

    #pragma unroll
    for (int ci = 0; ci < 2; ci++) {
        const int ct = wid * 2 + ci;
        const float bc = b2u[ct * 16 + colf];
        f32x4 acc[2];
        acc[0] = (f32x4){bc, bc, bc, bc};
        acc[1] = (f32x4){bc, bc, bc, bc};
        #pragma unroll
        for (int kb = 0; kb < 4; kb++) {
            bf16x8 bf = *(const bf16x8*)(pW2u + ((size_t)(ct * 4 + kb) * 64 + lane) * 8);
            #pragma unroll
            for (int rt = 0; rt < 2; rt++) {
                bf16x8 af = *(const bf16x8*)&t1[(rt * 16 + colf) * HSTR + kb * 32 + krow];
                acc[rt] = MFMA16(af, bf, acc[rt], 0, 0, 0);
            }
        }
        #pragma unroll
        for (int rt = 0; rt < 2; rt++)
            #pragma unroll
            for (int r = 0; r < 4; r++) {
                const int row = rt * 16 + (lane >> 4) * 4 + r;
                const size_t off = (size_t)(a0 + row) * FDIM + ct * 16 + colf;
                const float o = s_in[off] + silu_f(acc[rt][r]);
                s_out[off] = o;
                sbf_out[off] = f2bf(o);
            }
    }
}

// ---------------------------------------------------------------------------
__global__ void copyf4(float4* __restrict__ dst, const float4* __restrict__ src, int n4) {
    int i = blockIdx.x * blockDim.x + threadIdx.x;
    const int stride = gridDim.x * blockDim.x;
    for (; i < n4; i += stride) dst[i] = src[i];
}

__global__ void zerof4(float4* __restrict__ dst, int n4) {
    int i = blockIdx.x * blockDim.x + threadIdx.x;
    const int stride = gridDim.x * blockDim.x;
    const float4 z = make_float4(0.f, 0.f, 0.f, 0.f);
    for (; i < n4; i += stride) dst[i] = z;
}

__global__ void cvt_bf(const float* __restrict__ in, ushort_t* __restrict__ out, int n8) {
    int i = blockIdx.x * blockDim.x + threadIdx.x;
    if (i < n8) {
        const float4* s = (const float4*)(in + (size_t)i * 8);
        *(uint4*)(out + (size_t)i * 8) = cvt8(s[0], s[1]);
    }
}

// ---------------------------------------------------------------------------
extern "C" void kernel_launch(void* const* d_in, const int* in_sizes, int n_in,
                              void* d_out, int out_size, void* d_ws, size_t ws_size,
                              hipStream_t stream) {
    (void)in_sizes; (void)n_in; (void)out_size; (void)ws_size;

    const float* features = (const float*)d_in[0];
    const float* dists    = (const float*)d_in[1];
    const float* vecs     = (const float*)d_in[2];
    const float* cuts     = (const float*)d_in[3];
    const float* rbfs     = (const float*)d_in[4];
    const int*   idx_i    = (const int*)d_in[5];
    const int*   idx_j    = (const int*)d_in[6];
    const float* Wrbf     = (const float*)d_in[7];
    const float* Wemb     = (const float*)d_in[8];
    const float* eq0_W1   = (const float*)d_in[9];
    const float* eq0_b1   = (const float*)d_in[10];
    const float* eq0_W2   = (const float*)d_in[11];
    const float* eq1_W1   = (const float*)d_in[12];
    const float* eq1_b1   = (const float*)d_in[13];
    const float* eq1_W2   = (const float*)d_in[14];
    const float* inv_W1   = (const float*)d_in[15];
    const float* inv_b1   = (const float*)d_in[16];
    const float* inv_W2   = (const float*)d_in[17];
    const float* inv_b2   = (const float*)d_in[18];
    const float* upd_W1   = (const float*)d_in[19];
    const float* upd_b1   = (const float*)d_in[20];
    const float* upd_W2   = (const float*)d_in[21];
    const float* upd_b2   = (const float*)d_in[22];

    float*    sA  = (float*)d_ws;                       // NA*128
    float*    sB  = sA + (size_t)NA * FDIM;             // NA*128
    float*    vA  = sB + (size_t)NA * FDIM;             // NA*96 (zeros, pass-1 v_in)
    float*    vB  = vA + (size_t)NA * 96;               // NA*96 (v accum pass 1)
    ushort_t* sbf = (ushort_t*)(vB + (size_t)NA * 96);  // NA*128 ushort
    ushort_t* pwb = sbf + (size_t)NA * FDIM;            // PK_TOTAL*8 ushort

    float* s_final = (float*)d_out;
    float* v_final = s_final + (size_t)NA * FDIM;

    const int SN4 = NA * FDIM / 4;
    const int VN4 = NA * 96 / 4;

    pack_all<<<(PK_TOTAL + 255) / 256, 256, 0, stream>>>(
        eq0_W1, eq1_W1, inv_W1, eq0_W2, eq1_W2, inv_W2, Wrbf, Wemb, upd_W1, upd_W2, pwb);
    cvt_bf<<<(NA * FDIM / 8 + 255) / 256, 256, 0, stream>>>(features, sbf, NA * FDIM / 8);
    copyf4<<<1024, 256, 0, stream>>>((float4*)sB, (const float4*)features, SN4);
    zerof4<<<1024, 256, 0, stream>>>((float4*)vA, VN4);
    zerof4<<<1024, 256, 0, stream>>>((float4*)vB, VN4);

    // ---- block 0: edge reads (sbf, vA=0) -> accum (sB, vB); node: sB -> sA,sbf
    edge_kernel<<<PE / ET, 512, 0, stream>>>(
        rbfs, dists, vecs, cuts, idx_i, idx_j, sbf, vA,
        pwb + (size_t)PK_W1EQ0 * 8, eq0_b1, pwb + (size_t)PK_W2EQ0 * 8,
        pwb + (size_t)PK_W1INV0 * 8, inv_b1, pwb + (size_t)PK_W2INV0 * 8, inv_b2,
        sB, vB, 1);
    node_kernel<<<NA / AT, 256, 0, stream>>>(
        sB, pwb + (size_t)PK_WEMB * 8, pwb + (size_t)PK_W1U0 * 8, upd_b1,
        pwb + (size_t)PK_W2U0 * 8, upd_b2, sA, sbf);

    // ---- block 1: edge reads (sbf, vB) -> accum (sA, v_final); node: sA -> out
    copyf4<<<1024, 256, 0, stream>>>((float4*)v_final, (const float4*)vB, VN4);
    edge_kernel<<<PE / ET, 512, 0, stream>>>(
        rbfs, dists, vecs, cuts, idx_i, idx_j, sbf, vB,
        pwb + (size_t)PK_W1EQ1 * 8, eq1_b1, pwb + (size_t)PK_W2EQ1 * 8,
        pwb + (size_t)PK_W1INV1 * 8, inv_b1 + FDIM, pwb + (size_t)PK_W2INV1 * 8, inv_b2 + FDIM,
        sA, v_final, 0);
    node_kernel<<<NA / AT, 256, 0, stream>>>(
        sA, pwb + (size_t)PK_WEMB * 8, pwb + (size_t)PK_W1U1 * 8, upd_b1 + FDIM,
        pwb + (size_t)PK_W2U1 * 8, upd_b2 + FDIM, s_final, sbf);
}

// Round 6
// 569.942 us; speedup vs baseline: 1.8594x; 1.8594x over previous
//
#include <hip/hip_runtime.h>
#include <math.h>

#define NA   20000
#define PE   320000
#define FDIM 128
#define ET   64          // edges per block (edge kernel)
#define AT   32          // atoms per block (node kernel)

typedef unsigned short ushort_t;
typedef __attribute__((ext_vector_type(8))) short bf16x8;
typedef __attribute__((ext_vector_type(4))) float f32x4;
#define MFMA16 __builtin_amdgcn_mfma_f32_16x16x32_bf16

// ---------------- edge kernel LDS map (bytes) ----------------
// x' layout (words): [rbf 0:64 | a* 64:224 | si 224:352 | sj 352:480]
// XSTR=488: %8==0 (16B-aligned b128 rows), %32==8 (4-way bank pattern, cheap)
#define XSTR     488        // ushort stride
#define HSTR     136        // ushort stride; %8==0, %32==8
#define XS_OFF   0          // ushort [64][488]   (62464 B)
#define H1_OFF   62464      // ushort [64][136]   h1_eq -> h1_inv (17408 B)
#define US_OFF   79872      // float  [64][4]     ux,uy,uz,cut (1024 B)
#define IIS_OFF  80896      // int [65] (260 B)
#define JJS_OFF  81156      // int [64] (256 B)
#define SMEM_SZ  81416
// f32 aliases over xs (xs dead after GEMM1)
#define GL_OFF   0          // float [64][68]   g   (17408 B)
#define ML_OFF   17408      // float [64][132]  m   (33792 B, ends 51200 < 62464)

// ---------------- packed-weight fragment bases (1 frag = 8 ushort = 16B) ----
// fused W1: 15 kb x 8 ct x 64 lanes = 7680 frags
#define PK_W1EQ0   0
#define PK_W1EQ1   7680
#define PK_W1INV0  15360
#define PK_W1INV1  23040
#define PK_W2EQ0   30720    // 4kb x 4ct x 64 = 1024
#define PK_W2EQ1   31744
#define PK_W2INV0  32768    // 4kb x 8ct x 64 = 2048
#define PK_W2INV1  34816
#define PK_WEMB    36864    // 2048
#define PK_W1U0    38912    // 8kb x 8ct x 64 = 4096
#define PK_W1U1    43008
#define PK_W2U0    47104    // 2048
#define PK_W2U1    49152
#define PK_TOTAL   51200

__device__ __forceinline__ float silu_f(float z) {
    return z / (1.0f + __expf(-z));
}

__device__ __forceinline__ ushort_t f2bf(float x) {
    __bf16 h = (__bf16)x;
    union { __bf16 b; ushort_t u; } c; c.b = h; return c.u;
}

__device__ __forceinline__ unsigned int pack2bf(float x, float y) {
    return (unsigned int)f2bf(x) | ((unsigned int)f2bf(y) << 16);
}

__device__ __forceinline__ uint4 cvt8(float4 a, float4 b) {
    uint4 r;
    r.x = pack2bf(a.x, a.y); r.y = pack2bf(a.z, a.w);
    r.z = pack2bf(b.x, b.y); r.w = pack2bf(b.z, b.w);
    return r;
}

// ---------------------------------------------------------------------------
// Pack weights into bf16 MFMA B-fragment order.
// W1 sections are FUSED over x' = [rbf(64) | a*(160) | si(128) | sj(128)]:
//   row k<64:        Wrbf[k] @ W1[0:32]                  (dot only)
//   row 64<=k<224:   W1[k-32]                            (mode0) / 0 (mode1)
//   row k>=224:      W1direct + Wrbf[k-160] @ W1[0:32]
//   mode0 direct: W1[k-32]; mode1 (eq0, 288 rows): W1[k-192]
// ---------------------------------------------------------------------------
__global__ void pack_all(const float* __restrict__ eq0W1, const float* __restrict__ eq1W1,
                         const float* __restrict__ invW1, const float* __restrict__ eq0W2,
                         const float* __restrict__ eq1W2, const float* __restrict__ invW2,
                         const float* __restrict__ Wrbf,  const float* __restrict__ Wemb,
                         const float* __restrict__ updW1, const float* __restrict__ updW2,
                         ushort_t* __restrict__ out)
{
    const int tid = blockIdx.x * blockDim.x + threadIdx.x;
    if (tid >= PK_TOTAL) return;
    int base, KB, N, fused = 0, mode = 0;
    const float* src;
    if      (tid < PK_W1EQ1)  { base = PK_W1EQ0;  KB = 15; N = 128; src = eq0W1; fused = 1; mode = 1; }
    else if (tid < PK_W1INV0) { base = PK_W1EQ1;  KB = 15; N = 128; src = eq1W1; fused = 1; }
    else if (tid < PK_W1INV1) { base = PK_W1INV0; KB = 15; N = 128; src = invW1; fused = 1; }
    else if (tid < PK_W2EQ0)  { base = PK_W1INV1; KB = 15; N = 128; src = invW1 + 448 * 128; fused = 1; }
    else if (tid < PK_W2EQ1)  { base = PK_W2EQ0;  KB = 4;  N = 64;  src = eq0W2; }
    else if (tid < PK_W2INV0) { base = PK_W2EQ1;  KB = 4;  N = 64;  src = eq1W2; }
    else if (tid < PK_W2INV1) { base = PK_W2INV0; KB = 4;  N = 128; src = invW2; }
    else if (tid < PK_WEMB)   { base = PK_W2INV1; KB = 4;  N = 128; src = invW2 + 128 * 128; }
    else if (tid < PK_W1U0)   { base = PK_WEMB;   KB = 4;  N = 128; src = Wemb; }
    else if (tid < PK_W1U1)   { base = PK_W1U0;   KB = 8;  N = 128; src = updW1; }
    else if (tid < PK_W2U0)   { base = PK_W1U1;   KB = 8;  N = 128; src = updW1 + 256 * 128; }
    else if (tid < PK_W2U1)   { base = PK_W2U0;   KB = 4;  N = 128; src = updW2; }
    else                      { base = PK_W2U1;   KB = 4;  N = 128; src = updW2 + 128 * 128; }
    const int local = tid - base;
    const int lane  = local & 63;
    const int rest  = local >> 6;
    const int kb    = rest % KB;
    const int ct    = rest / KB;
    const int col   = ct * 16 + (lane & 15);
    const int k0    = kb * 32 + ((lane >> 4) * 8);
    ushort_t v[8];
    #pragma unroll
    for (int j = 0; j < 8; j++) {
        const int k = k0 + j;
        float x;
        if (!fused) {
            x = src[(size_t)k * N + col];
        } else {
            x = 0.f;
            const int di = (mode == 0) ? (k >= 64 ? k - 32 : -1)
                                       : (k >= 224 ? k - 192 : -1);
            if (di >= 0) x = src[(size_t)di * 128 + col];
            const int dr = (k < 64) ? k : (k >= 224 ? k - 160 : -1);
            if (dr >= 0) {
                float s = 0.f;
                for (int q = 0; q < 32; q++)
                    s += Wrbf[dr * 32 + q] * src[(size_t)q * 128 + col];
                x += s;
            }
        }
        v[j] = f2bf(x);
    }
    *(uint4*)(out + (size_t)tid * 8) = *(uint4*)v;
}

// ---------------------------------------------------------------------------
// Fused MFMA edge kernel. 64 edges/block, 512 threads (8 waves), 2 blocks/CU.
// eqSkip=1 also implies v_in == 0 (pass 1): a_* phase and kb 2..6 skipped.
// ---------------------------------------------------------------------------
__global__ __launch_bounds__(512, 4)
void edge_kernel(const float* __restrict__ rbfs,
                 const float* __restrict__ dists,
                 const float* __restrict__ vecs,
                 const float* __restrict__ cuts,
                 const int*   __restrict__ gidx_i,
                 const int*   __restrict__ gidx_j,
                 const ushort_t* __restrict__ s_bf,    // bf16 mirror of s
                 const float* __restrict__ v_in,
                 const ushort_t* __restrict__ pW1eq,
                 const float* __restrict__ b1eq,
                 const ushort_t* __restrict__ pW2eq,
                 const ushort_t* __restrict__ pW1inv,
                 const float* __restrict__ b1inv,
                 const ushort_t* __restrict__ pW2inv,
                 const float* __restrict__ b2inv,
                 float* __restrict__ s_out,
                 float* __restrict__ v_out,
                 const int eqSkip)
{
    __shared__ __align__(16) char smem[SMEM_SZ];
    ushort_t* xs  = (ushort_t*)(smem + XS_OFF);
    ushort_t* h1  = (ushort_t*)(smem + H1_OFF);
    float*    us  = (float*)(smem + US_OFF);
    int*      iis = (int*)(smem + IIS_OFF);
    int*      jjs = (int*)(smem + JJS_OFF);
    float*    gl  = (float*)(smem + GL_OFF);
    float*    ml  = (float*)(smem + ML_OFF);

    const int t    = threadIdx.x;
    // XCD-aware swizzle: 5000 blocks = 8 XCDs x 625 contiguous chunks
    const int bid  = blockIdx.x;
    const int p0   = ((bid & 7) * 625 + (bid >> 3)) * ET;
    const int lane = t & 63;
    const int wid  = t >> 6;
    const int colf = lane & 15;
    const int krow = (lane >> 4) * 8;

    // ------- phase 0: stage rbf/si/sj -> xs, us/iis/jjs; a_* (pass 2 only) ----
    {
        const int e = t >> 3, l = t & 7;
        const int p = p0 + e;
        const int i = gidx_i[p];
        const int j = gidx_j[p];
        const uint4* si4 = (const uint4*)(s_bf + (size_t)i * FDIM);
        const uint4* sj4 = (const uint4*)(s_bf + (size_t)j * FDIM);
        *(uint4*)&xs[e * XSTR + 224 + l * 16]     = si4[l * 2];
        *(uint4*)&xs[e * XSTR + 224 + l * 16 + 8] = si4[l * 2 + 1];
        *(uint4*)&xs[e * XSTR + 352 + l * 16]     = sj4[l * 2];
        *(uint4*)&xs[e * XSTR + 352 + l * 16 + 8] = sj4[l * 2 + 1];
        const float4* rb4 = (const float4*)(rbfs + (size_t)p * 64);
        float4 r0 = rb4[l * 2], r1 = rb4[l * 2 + 1];
        *(uint4*)&xs[e * XSTR + l * 8] = cvt8(r0, r1);
        if (t < ET) {
            const int pp = p0 + t;
            const float dinv = 1.0f / (dists[pp] + 0.001f);
            float4 uu;
            uu.x = vecs[pp * 3 + 0] * dinv;
            uu.y = vecs[pp * 3 + 1] * dinv;
            uu.z = vecs[pp * 3 + 2] * dinv;
            uu.w = cuts[pp];
            *(float4*)&us[t * 4] = uu;
            jjs[t] = gidx_j[pp];
        }
        if (t < ET + 1) {
            const int pp = p0 + t;
            iis[t] = (pp < PE) ? gidx_i[pp] : -1;
        }
        if (!eqSkip) {
            // a_* terms -> xs cols [64,224)
            const int m0 = (t & 7) * 4;
            const float dinv = 1.0f / (dists[p] + 0.001f);
            const float ux = vecs[p * 3 + 0] * dinv;
            const float uy = vecs[p * 3 + 1] * dinv;
            const float uz = vecs[p * 3 + 2] * dinv;
            float vi[3][4], vj[3][4];
            #pragma unroll
            for (int d = 0; d < 3; d++) {
                const float4 a = *(const float4*)(v_in + (size_t)i * 96 + d * 32 + m0);
                const float4 b = *(const float4*)(v_in + (size_t)j * 96 + d * 32 + m0);
                vi[d][0] = a.x; vi[d][1] = a.y; vi[d][2] = a.z; vi[d][3] = a.w;
                vj[d][0] = b.x; vj[d][1] = b.y; vj[d][2] = b.z; vj[d][3] = b.w;
            }
            float aui[4], auj[4], aij[4], aii[4], ajj[4];
            #pragma unroll
            for (int mm = 0; mm < 4; mm++) {
                aui[mm] = ux * vi[0][mm] + uy * vi[1][mm] + uz * vi[2][mm];
                auj[mm] = ux * vj[0][mm] + uy * vj[1][mm] + uz * vj[2][mm];
                aij[mm] = vi[0][mm] * vj[0][mm] + vi[1][mm] * vj[1][mm] + vi[2][mm] * vj[2][mm];
                aii[mm] = vi[0][mm] * vi[0][mm] + vi[1][mm] * vi[1][mm] + vi[2][mm] * vi[2][mm];
                ajj[mm] = vj[0][mm] * vj[0][mm] + vj[1][mm] * vj[1][mm] + vj[2][mm] * vj[2][mm];
            }
            uint2 w;
            w.x = pack2bf(aui[0], aui[1]); w.y = pack2bf(aui[2], aui[3]);
            *(uint2*)&xs[e * XSTR + 64 + m0] = w;
            w.x = pack2bf(auj[0], auj[1]); w.y = pack2bf(auj[2], auj[3]);
            *(uint2*)&xs[e * XSTR + 96 + m0] = w;
            w.x = pack2bf(aij[0], aij[1]); w.y = pack2bf(aij[2], aij[3]);
            *(uint2*)&xs[e * XSTR + 128 + m0] = w;
            w.x = pack2bf(aii[0], aii[1]); w.y = pack2bf(aii[2], aii[3]);
            *(uint2*)&xs[e * XSTR + 160 + m0] = w;
            w.x = pack2bf(ajj[0], ajj[1]); w.y = pack2bf(ajj[2], ajj[3]);
            *(uint2*)&xs[e * XSTR + 192 + m0] = w;
        }
    }
    __syncthreads();   // B1: x' complete

    // ------- GEMM1 (fused eq+inv): 15 kb over x' ------------------------------
    f32x4 ainv[4];
    {
        f32x4 aeq[4];
        const float bce = b1eq[wid * 16 + colf];
        const float bci = b1inv[wid * 16 + colf];
        #pragma unroll
        for (int rt = 0; rt < 4; rt++) {
            aeq[rt]  = (f32x4){bce, bce, bce, bce};
            ainv[rt] = (f32x4){bci, bci, bci, bci};
        }
        #pragma unroll
        for (int kb = 0; kb < 15; kb++) {
            if (eqSkip && kb >= 2 && kb < 7) continue;   // a* rows are zero in pass 1
            bf16x8 af[4];
            #pragma unroll
            for (int rt = 0; rt < 4; rt++)
                af[rt] = *(const bf16x8*)&xs[(rt * 16 + colf) * XSTR + kb * 32 + krow];
            bf16x8 bi = *(const bf16x8*)(pW1inv + ((size_t)(wid * 15 + kb) * 64 + lane) * 8);
            #pragma unroll
            for (int rt = 0; rt < 4; rt++)
                ainv[rt] = MFMA16(af[rt], bi, ainv[rt], 0, 0, 0);
            bf16x8 be = *(const bf16x8*)(pW1eq + ((size_t)(wid * 15 + kb) * 64 + lane) * 8);
            #pragma unroll
            for (int rt = 0; rt < 4; rt++)
                aeq[rt] = MFMA16(af[rt], be, aeq[rt], 0, 0, 0);
        }
        #pragma unroll
        for (int rt = 0; rt < 4; rt++)
            #pragma unroll
            for (int r = 0; r < 4; r++) {
                const int row = rt * 16 + (lane >> 4) * 4 + r;
                h1[row * HSTR + wid * 16 + colf] = f2bf(silu_f(aeq[rt][r]));
            }
    }
    __syncthreads();   // B2: h1_eq ready; xs dead (gl/ml aliases free)

    // ------- GEMM2-eq: g = h1_eq @ W2eq -> gl (xs alias) ----------------------
    {
        const int ct2 = wid & 3;
        const int rh  = wid >> 2;
        f32x4 gacc[2];
        gacc[0] = (f32x4){0.f, 0.f, 0.f, 0.f};
        gacc[1] = (f32x4){0.f, 0.f, 0.f, 0.f};
        #pragma unroll
        for (int kb = 0; kb < 4; kb++) {
            bf16x8 bf = *(const bf16x8*)(pW2eq + ((size_t)(ct2 * 4 + kb) * 64 + lane) * 8);
            #pragma unroll
            for (int q = 0; q < 2; q++) {
                bf16x8 af = *(const bf16x8*)&h1[((rh * 2 + q) * 16 + colf) * HSTR + kb * 32 + krow];
                gacc[q] = MFMA16(af, bf, gacc[q], 0, 0, 0);
            }
        }
        #pragma unroll
        for (int q = 0; q < 2; q++)
            #pragma unroll
            for (int r = 0; r < 4; r++) {
                const int row = (rh * 2 + q) * 16 + (lane >> 4) * 4 + r;
                gl[row * 68 + ct2 * 16 + colf] = gacc[q][r];
            }
    }
    __syncthreads();   // B3: h1_eq reads done

    // ------- write h1_inv -----------------------------------------------------
    {
        #pragma unroll
        for (int rt = 0; rt < 4; rt++)
            #pragma unroll
            for (int r = 0; r < 4; r++) {
                const int row = rt * 16 + (lane >> 4) * 4 + r;
                h1[row * HSTR + wid * 16 + colf] = f2bf(silu_f(ainv[rt][r]));
            }
    }
    __syncthreads();   // B4: h1_inv ready

    // ------- GEMM2-inv: m = silu(h1_inv @ W2inv + b2) * cut -> ml (xs alias) --
    {
        f32x4 macc[4];
        const float bc = b2inv[wid * 16 + colf];
        #pragma unroll
        for (int rt = 0; rt < 4; rt++) macc[rt] = (f32x4){bc, bc, bc, bc};
        #pragma unroll
        for (int kb = 0; kb < 4; kb++) {
            bf16x8 bf = *(const bf16x8*)(pW2inv + ((size_t)(wid * 4 + kb) * 64 + lane) * 8);
            #pragma unroll
            for (int rt = 0; rt < 4; rt++) {
                bf16x8 af = *(const bf16x8*)&h1[(rt * 16 + colf) * HSTR + kb * 32 + krow];
                macc[rt] = MFMA16(af, bf, macc[rt], 0, 0, 0);
            }
        }
        #pragma unroll
        for (int rt = 0; rt < 4; rt++)
            #pragma unroll
            for (int r = 0; r < 4; r++) {
                const int row = rt * 16 + (lane >> 4) * 4 + r;
                ml[row * 132 + wid * 16 + colf] = silu_f(macc[rt][r]) * us[row * 4 + 3];
            }
    }
    __syncthreads();   // B5: ml/gl ready

    // ------- sorted-run scan + scatter (4 x 16-edge quarters) -----------------
    {
        // s columns: 512 threads = 4 quarters x 128 cols, 16 iters
        const int qq = t >> 7;
        const int c  = t & 127;
        const int e0 = qq * 16;
        float acc = 0.f;
        #pragma unroll
        for (int e = e0; e < e0 + 16; e++) {
            acc += ml[e * 132 + c];
            if (e == e0 + 15 || iis[e + 1] != iis[e]) {
                atomicAdd(&s_out[(size_t)iis[e] * FDIM + c], acc);
                acc = 0.f;
            }
        }
    }
    if (t < 384) {
        // v columns: 4 quarters x 96 cols, 16 iters
        const int qq  = t / 96;
        const int c   = t - qq * 96;
        const int d   = c >> 5;
        const int mm  = c & 31;
        const int e0  = qq * 16;
        float acc = 0.f;
        #pragma unroll
        for (int e = e0; e < e0 + 16; e++) {
            const float g0  = gl[e * 68 + mm];
            const float g1  = gl[e * 68 + 32 + mm];
            const float vjv = v_in[(size_t)jjs[e] * 96 + c];
            acc = fmaf(us[e * 4 + 3], fmaf(g0, us[e * 4 + d], g1 * vjv), acc);
            if (e == e0 + 15 || iis[e + 1] != iis[e]) {
                atomicAdd(&v_out[(size_t)iis[e] * 96 + c], acc);
                acc = 0.f;
            }
        }
    }
}

// ---------------------------------------------------------------------------
// MFMA node update: s_out = s_in + silu(silu([s,s@Wemb]@W1u+b1u)@W2u+b2u)
// ---------------------------------------------------------------------------
__global__ __launch_bounds__(256, 6)
void node_kernel(const float* __restrict__ s_in,
                 const ushort_t* __restrict__ pWemb,
                 const ushort_t* __restrict__ pW1u,
                 const float* __restrict__ b1u,
                 const ushort_t* __restrict__ pW2u,
                 const float* __restrict__ b2u,
                 float* __restrict__ s_out,
                 ushort_t* __restrict__ sbf_out)
{
    __shared__ ushort_t ss[AT * HSTR];
    __shared__ ushort_t fe[AT * HSTR];
    __shared__ ushort_t t1[AT * HSTR];
    const int t    = threadIdx.x;
    const int a0   = blockIdx.x * AT;
    const int lane = t & 63;
    const int wid  = t >> 6;
    const int colf = lane & 15;
    const int krow = (lane >> 4) * 8;

    {
        const int a = t >> 3, l = t & 7;
        const float4* sr = (const float4*)(s_in + (size_t)(a0 + a) * FDIM);
        float4 q0 = sr[l * 4 + 0], q1 = sr[l * 4 + 1], q2 = sr[l * 4 + 2], q3 = sr[l * 4 + 3];
        *(uint4*)&ss[a * HSTR + l * 16]     = cvt8(q0, q1);
        *(uint4*)&ss[a * HSTR + l * 16 + 8] = cvt8(q2, q3);
    }
    __syncthreads();

    #pragma unroll
    for (int ci = 0; ci < 2; ci++) {
        const int ct = wid * 2 + ci;
        f32x4 acc[2];
        acc[0] = (f32x4){0.f, 0.f, 0.f, 0.f};
        acc[1] = (f32x4){0.f, 0.f, 0.f, 0.f};
        #pragma unroll
        for (int kb = 0; kb < 4; kb++) {
            bf16x8 bf = *(const bf16x8*)(pWemb + ((size_t)(ct * 4 + kb) * 64 + lane) * 8);
            #pragma unroll
            for (int rt = 0; rt < 2; rt++) {
                bf16x8 af = *(const bf16x8*)&ss[(rt * 16 + colf) * HSTR + kb * 32 + krow];
                acc[rt] = MFMA16(af, bf, acc[rt], 0, 0, 0);
            }
        }
        #pragma unroll
        for (int rt = 0; rt < 2; rt++)
            #pragma unroll
            for (int r = 0; r < 4; r++) {
                const int row = rt * 16 + (lane >> 4) * 4 + r;
                fe[row * HSTR + ct * 16 + colf] = f2bf(acc[rt][r]);
            }
    }
    __syncthreads();

    #pragma unroll
    for (int ci = 0; ci < 2; ci++) {
        const int ct = wid * 2 + ci;
        const float bc = b1u[ct * 16 + colf];
        f32x4 acc[2];
        acc[0] = (f32x4){bc, bc, bc, bc};
        acc[1] = (f32x4){bc, bc, bc, bc};
        #pragma unroll
        for (int kb = 0; kb < 8; kb++) {
            bf16x8 bf = *(const bf16x8*)(pW1u + ((size_t)(ct * 8 + kb) * 64 + lane) * 8);
            #pragma unroll
            for (int rt = 0; rt < 2; rt++) {
                bf16x8 af;
                if (kb < 4) af = *(const bf16x8*)&ss[(rt * 16 + colf) * HSTR + kb * 32 + krow];
                else        af = *(const bf16x8*)&fe[(rt * 16 + colf) * HSTR + (kb - 4) * 32 + krow];
                acc[rt] = MFMA16(af, bf, acc[rt], 0, 0, 0);
            }
        }
        #pragma unroll
        for (int rt = 0; rt < 2; rt++)
            #pragma unroll
            for (int r = 0; r < 4; r++) {
                const int row = rt * 16 + (lane >> 4) * 4 + r;
                t1[row * HSTR + ct * 16 + colf] = f2bf(silu_f(acc[rt][r]));
            }
    }
    __syncthreads();

    #pragma unroll
    for (int ci = 0; ci < 2; ci++) {
        const int ct = wid * 2 + ci;
        const float bc = b2u[ct * 16 + colf];
        f32x4 acc[2];
        acc[0] = (f32x4){bc, bc, bc, bc};
        acc[1] = (f32x4){bc, bc, bc, bc};
        #pragma unroll
        for (int kb = 0; kb < 4; kb++) {
            bf16x8 bf = *(const bf16x8*)(pW2u + ((size_t)(ct * 4 + kb) * 64 + lane) * 8);
            #pragma unroll
            for (int rt = 0; rt < 2; rt++) {
                bf16x8 af = *(const bf16x8*)&t1[(rt * 16 + colf) * HSTR + kb * 32 + krow];
                acc[rt] = MFMA16(af, bf, acc[rt], 0, 0, 0);
            }
        }
        #pragma unroll
        for (int rt = 0; rt < 2; rt++)
            #pragma unroll
            for (int r = 0; r < 4; r++) {
                const int row = rt * 16 + (lane >> 4) * 4 + r;
                const size_t off = (size_t)(a0 + row) * FDIM + ct * 16 + colf;
                const float o = s_in[off] + silu_f(acc[rt][r]);
                s_out[off] = o;
                sbf_out[off] = f2bf(o);
            }
    }
}

// ---------------------------------------------------------------------------
__global__ void copyf4(float4* __restrict__ dst, const float4* __restrict__ src, int n4) {
    int i = blockIdx.x * blockDim.x + threadIdx.x;
    const int stride = gridDim.x * blockDim.x;
    for (; i < n4; i += stride) dst[i] = src[i];
}

__global__ void zerof4(float4* __restrict__ dst, int n4) {
    int i = blockIdx.x * blockDim.x + threadIdx.x;
    const int stride = gridDim.x * blockDim.x;
    const float4 z = make_float4(0.f, 0.f, 0.f, 0.f);
    for (; i < n4; i += stride) dst[i] = z;
}

__global__ void cvt_bf(const float* __restrict__ in, ushort_t* __restrict__ out, int n8) {
    int i = blockIdx.x * blockDim.x + threadIdx.x;
    if (i < n8) {
        const float4* s = (const float4*)(in + (size_t)i * 8);
        *(uint4*)(out + (size_t)i * 8) = cvt8(s[0], s[1]);
    }
}

// ---------------------------------------------------------------------------
extern "C" void kernel_launch(void* const* d_in, const int* in_sizes, int n_in,
                              void* d_out, int out_size, void* d_ws, size_t ws_size,
                              hipStream_t stream) {
    (void)in_sizes; (void)n_in; (void)out_size; (void)ws_size;

    const float* features = (const float*)d_in[0];
    const float* dists    = (const float*)d_in[1];
    const float* vecs     = (const float*)d_in[2];
    const float* cuts     = (const float*)d_in[3];
    const float* rbfs     = (const float*)d_in[4];
    const int*   idx_i    = (const int*)d_in[5];
    const int*   idx_j    = (const int*)d_in[6];
    const float* Wrbf     = (const float*)d_in[7];
    const float* Wemb     = (const float*)d_in[8];
    const float* eq0_W1   = (const float*)d_in[9];
    const float* eq0_b1   = (const float*)d_in[10];
    const float* eq0_W2   = (const float*)d_in[11];
    const float* eq1_W1   = (const float*)d_in[12];
    const float* eq1_b1   = (const float*)d_in[13];
    const float* eq1_W2   = (const float*)d_in[14];
    const float* inv_W1   = (const float*)d_in[15];
    const float* inv_b1   = (const float*)d_in[16];
    const float* inv_W2   = (const float*)d_in[17];
    const float* inv_b2   = (const float*)d_in[18];
    const float* upd_W1   = (const float*)d_in[19];
    const float* upd_b1   = (const float*)d_in[20];
    const float* upd_W2   = (const float*)d_in[21];
    const float* upd_b2   = (const float*)d_in[22];

    float*    sA  = (float*)d_ws;                       // NA*128
    float*    sB  = sA + (size_t)NA * FDIM;             // NA*128
    float*    vA  = sB + (size_t)NA * FDIM;             // NA*96 (zeros, pass-1 v_in)
    float*    vB  = vA + (size_t)NA * 96;               // NA*96 (v accum pass 1)
    ushort_t* sbf = (ushort_t*)(vB + (size_t)NA * 96);  // NA*128 ushort
    ushort_t* pwb = sbf + (size_t)NA * FDIM;            // PK_TOTAL*8 ushort

    float* s_final = (float*)d_out;
    float* v_final = s_final + (size_t)NA * FDIM;

    const int SN4 = NA * FDIM / 4;
    const int VN4 = NA * 96 / 4;

    pack_all<<<(PK_TOTAL + 255) / 256, 256, 0, stream>>>(
        eq0_W1, eq1_W1, inv_W1, eq0_W2, eq1_W2, inv_W2, Wrbf, Wemb, upd_W1, upd_W2, pwb);
    cvt_bf<<<(NA * FDIM / 8 + 255) / 256, 256, 0, stream>>>(features, sbf, NA * FDIM / 8);
    copyf4<<<1024, 256, 0, stream>>>((float4*)sB, (const float4*)features, SN4);
    zerof4<<<1024, 256, 0, stream>>>((float4*)vA, VN4);
    zerof4<<<1024, 256, 0, stream>>>((float4*)vB, VN4);

    // ---- block 0: edge reads (sbf, vA=0) -> accum (sB, vB); node: sB -> sA,sbf
    edge_kernel<<<PE / ET, 512, 0, stream>>>(
        rbfs, dists, vecs, cuts, idx_i, idx_j, sbf, vA,
        pwb + (size_t)PK_W1EQ0 * 8, eq0_b1, pwb + (size_t)PK_W2EQ0 * 8,
        pwb + (size_t)PK_W1INV0 * 8, inv_b1, pwb + (size_t)PK_W2INV0 * 8, inv_b2,
        sB, vB, 1);
    node_kernel<<<NA / AT, 256, 0, stream>>>(
        sB, pwb + (size_t)PK_WEMB * 8, pwb + (size_t)PK_W1U0 * 8, upd_b1,
        pwb + (size_t)PK_W2U0 * 8, upd_b2, sA, sbf);

    // ---- block 1: edge reads (sbf, vB) -> accum (sA, v_final); node: sA -> out
    copyf4<<<1024, 256, 0, stream>>>((float4*)v_final, (const float4*)vB, VN4);
    edge_kernel<<<PE / ET, 512, 0, stream>>>(
        rbfs, dists, vecs, cuts, idx_i, idx_j, sbf, vB,
        pwb + (size_t)PK_W1EQ1 * 8, eq1_b1, pwb + (size_t)PK_W2EQ1 * 8,
        pwb + (size_t)PK_W1INV1 * 8, inv_b1 + FDIM, pwb + (size_t)PK_W2INV1 * 8, inv_b2 + FDIM,
        sA, v_final, 0);
    node_kernel<<<NA / AT, 256, 0, stream>>>(
        sA, pwb + (size_t)PK_WEMB * 8, pwb + (size_t)PK_W1U1 * 8, upd_b1 + FDIM,
        pwb + (size_t)PK_W2U1 * 8, upd_b2 + FDIM, s_final, sbf);
}